// Round 1
// baseline (17.356 us; speedup 1.0000x reference)
//
#include <hip/hip_runtime.h>

// Per-node partial dot products:
//   tabA[n] = ( dot(h[n], W[0][0:128]),  dot(h[n], W[1][0:128])  )
//   tabB[n] = ( dot(h[n], W[0][128:256]), dot(h[n], W[1][128:256]) )
// 4 threads per node; thread `quad` handles elements d = quad*4 + 16k + j
// (j=0..3, k=0..7) -> adjacent lanes read adjacent 16B chunks (coalesced),
// LDS reads hit distinct banks across quads.
__global__ __launch_bounds__(256) void node_dots_kernel(
    const float* __restrict__ h, const float* __restrict__ W,
    float2* __restrict__ tabA, float2* __restrict__ tabB, int n_nodes) {
  __shared__ float sW[512];  // W is [2][256] = 512 floats = 2 KB
  const int tid = threadIdx.x;
  if (tid < 128) {
    reinterpret_cast<float4*>(sW)[tid] = reinterpret_cast<const float4*>(W)[tid];
  }
  __syncthreads();

  const int node = blockIdx.x * 64 + (tid >> 2);
  if (node >= n_nodes) return;
  const int quad = tid & 3;
  const float* hrow = h + (size_t)node * 128;

  float a0 = 0.f, a1 = 0.f, b0 = 0.f, b1 = 0.f;
#pragma unroll
  for (int k = 0; k < 8; ++k) {
    const int d = quad * 4 + k * 16;
    const float4 hv = *reinterpret_cast<const float4*>(hrow + d);
    const float4 w0 = *reinterpret_cast<const float4*>(sW + d);        // W[0][d..]
    const float4 w1 = *reinterpret_cast<const float4*>(sW + 256 + d);  // W[1][d..]
    const float4 w2 = *reinterpret_cast<const float4*>(sW + 128 + d);  // W[0][128+d..]
    const float4 w3 = *reinterpret_cast<const float4*>(sW + 384 + d);  // W[1][128+d..]
    a0 += hv.x * w0.x + hv.y * w0.y + hv.z * w0.z + hv.w * w0.w;
    a1 += hv.x * w1.x + hv.y * w1.y + hv.z * w1.z + hv.w * w1.w;
    b0 += hv.x * w2.x + hv.y * w2.y + hv.z * w2.z + hv.w * w2.w;
    b1 += hv.x * w3.x + hv.y * w3.y + hv.z * w3.z + hv.w * w3.w;
  }
  // reduce across the 4 lanes of this node's quad group
  a0 += __shfl_xor(a0, 1); a0 += __shfl_xor(a0, 2);
  a1 += __shfl_xor(a1, 1); a1 += __shfl_xor(a1, 2);
  b0 += __shfl_xor(b0, 1); b0 += __shfl_xor(b0, 2);
  b1 += __shfl_xor(b1, 1); b1 += __shfl_xor(b1, 2);
  if (quad == 0) {
    tabA[node] = make_float2(a0, a1);
    tabB[node] = make_float2(b0, b1);
  }
}

// Edge pass: score[e] = tabA[src[e]] + tabB[dst[e]] + bias. Tables are
// 400 KB each -> L1/L2 resident; indices + output are coalesced streams.
__global__ __launch_bounds__(256) void edge_scores_kernel(
    const int* __restrict__ src, const int* __restrict__ dst,
    const float2* __restrict__ tabA, const float2* __restrict__ tabB,
    const float* __restrict__ bias, float2* __restrict__ out, int n_edges) {
  const int e = blockIdx.x * blockDim.x + threadIdx.x;
  if (e >= n_edges) return;
  const float bx = bias[0], by = bias[1];
  const int s = src[e];
  const int d = dst[e];
  const float2 a = tabA[s];
  const float2 b = tabB[d];
  out[e] = make_float2(a.x + b.x + bx, a.y + b.y + by);
}

// Fallback if d_ws is too small: direct per-edge gather + dot (slower but
// correct; h is L3-resident so still bounded by L2/L3 gather BW).
__global__ __launch_bounds__(256) void edge_direct_kernel(
    const float* __restrict__ h, const int* __restrict__ src,
    const int* __restrict__ dst, const float* __restrict__ W,
    const float* __restrict__ bias, float2* __restrict__ out, int n_edges) {
  __shared__ float sW[512];
  const int tid = threadIdx.x;
  if (tid < 128) {
    reinterpret_cast<float4*>(sW)[tid] = reinterpret_cast<const float4*>(W)[tid];
  }
  __syncthreads();
  const int e = blockIdx.x * blockDim.x + tid;
  if (e >= n_edges) return;
  const float* hu = h + (size_t)src[e] * 128;
  const float* hv = h + (size_t)dst[e] * 128;
  float s0 = bias[0], s1 = bias[1];
#pragma unroll 4
  for (int d = 0; d < 128; d += 4) {
    const float4 u = *reinterpret_cast<const float4*>(hu + d);
    const float4 v = *reinterpret_cast<const float4*>(hv + d);
    const float4 w00 = *reinterpret_cast<const float4*>(sW + d);
    const float4 w01 = *reinterpret_cast<const float4*>(sW + 128 + d);
    const float4 w10 = *reinterpret_cast<const float4*>(sW + 256 + d);
    const float4 w11 = *reinterpret_cast<const float4*>(sW + 384 + d);
    s0 += u.x * w00.x + u.y * w00.y + u.z * w00.z + u.w * w00.w
        + v.x * w01.x + v.y * w01.y + v.z * w01.z + v.w * w01.w;
    s1 += u.x * w10.x + u.y * w10.y + u.z * w10.z + u.w * w10.w
        + v.x * w11.x + v.y * w11.y + v.z * w11.z + v.w * w11.w;
  }
  out[e] = make_float2(s0, s1);
}

extern "C" void kernel_launch(void* const* d_in, const int* in_sizes, int n_in,
                              void* d_out, int out_size, void* d_ws, size_t ws_size,
                              hipStream_t stream) {
  const float* h    = (const float*)d_in[0];
  const int*   src  = (const int*)d_in[1];
  const int*   dst  = (const int*)d_in[2];
  const float* W    = (const float*)d_in[3];
  const float* bias = (const float*)d_in[4];
  float2* out = (float2*)d_out;

  const int n_nodes = in_sizes[0] / 128;
  const int n_edges = in_sizes[1];

  const size_t need = (size_t)n_nodes * 4 * sizeof(float);  // tabA + tabB
  if (ws_size >= need) {
    float2* tabA = (float2*)d_ws;
    float2* tabB = tabA + n_nodes;
    node_dots_kernel<<<(n_nodes + 63) / 64, 256, 0, stream>>>(h, W, tabA, tabB, n_nodes);
    edge_scores_kernel<<<(n_edges + 255) / 256, 256, 0, stream>>>(
        src, dst, tabA, tabB, bias, out, n_edges);
  } else {
    edge_direct_kernel<<<(n_edges + 255) / 256, 256, 0, stream>>>(
        h, src, dst, W, bias, out, n_edges);
  }
}